// Round 11
// baseline (743.188 us; speedup 1.0000x reference)
//
#include <hip/hip_runtime.h>
#include <hip/hip_bf16.h>
#include <math.h>

// Problem constants
#define TT 64
#define BB 256      // per-sequence batch
#define BT 512      // total batch (both sequences)
#define DD 300      // embedding dim
#define HH 512      // hidden
#define G4 2048     // 4*H
#define KX 320      // padded x-region K
#define KW 512      // physical W-hi K (read twice: A = [h_hi | h_lo])
#define KC 64       // K chunk per LDS stage
#define NCHX 5      // KX / KC
#define NCHH 16     // 1024 / KC (2-term: hi*Whi + lo*Whi)

typedef __attribute__((ext_vector_type(8))) short short8v;
typedef __attribute__((ext_vector_type(4))) float f32x4;
typedef __attribute__((ext_vector_type(4))) unsigned short ushort4v;

__device__ __forceinline__ unsigned short f2bf(float f) {
    union { float f; unsigned int u; } v; v.f = f;
    unsigned int u = v.u;
    u += 0x7fffu + ((u >> 16) & 1u);   // round-to-nearest-even
    return (unsigned short)(u >> 16);
}
__device__ __forceinline__ float bf2f(unsigned short s) {
    union { unsigned int u; float f; } v; v.u = ((unsigned int)s) << 16;
    return v.f;
}
__device__ __forceinline__ float sigm(float x) { return 1.0f / (1.0f + __expf(-x)); }
__device__ __forceinline__ float tanh_f(float x) {
    float ax = fabsf(x);
    if (ax > 15.0f) return (x > 0.0f) ? 1.0f : -1.0f;
    float e = __expf(2.0f * ax);
    float t = 1.0f - 2.0f / (e + 1.0f);
    return (x >= 0.0f) ? t : -t;
}

// ---------------------------------------------------------------------------
// Prep:
//  WcatP[g''][KW]: g'' = 4*j + gate (R9-verified layout), source g = gate*512+j,
//    K = [0,512) = Whh hi only (2-term split).
//  WihP (gemm_x layout, R4-verified): row g'O = jt*64 + grp*16 + jj.
//  biasP[g''] = b_ih[g] + b_hh[g]  (same values as jt*64+jj*4+grp form).
__global__ __launch_bounds__(256) void prep_w(const float* __restrict__ Wih,
                                              const float* __restrict__ Whh,
                                              const float* __restrict__ bih,
                                              const float* __restrict__ bhh,
                                              unsigned short* __restrict__ WcatP,
                                              unsigned short* __restrict__ WihP,
                                              float* __restrict__ biasP)
{
    const int gp = blockIdx.x;            // g'' 0..2047
    const int jN = gp >> 2, gateN = gp & 3;
    const int gN = gateN * 512 + jN;
    // old decode for WihP
    const int jt = gp >> 6, r = gp & 63;
    const int grpO = r >> 4, jjO = r & 15;
    const int gO = grpO * 512 + jt * 16 + jjO;

    for (int k = threadIdx.x; k < KW; k += 256)
        WcatP[(size_t)gp * KW + k] = f2bf(Whh[(size_t)gN * HH + k]);
    for (int k = threadIdx.x; k < KX; k += 256)
        WihP[(size_t)gp * KX + k] = (k < DD) ? f2bf(Wih[(size_t)gO * DD + k])
                                             : (unsigned short)0;
    if (threadIdx.x == 0) biasP[gp] = bih[gN] + bhh[gN];
}

// Prep: initial h (hi/lo bf16) and c.
__global__ __launch_bounds__(256) void prep_h(const float* __restrict__ h0a,
                                              const float* __restrict__ c0a,
                                              const float* __restrict__ h0b,
                                              const float* __restrict__ c0b,
                                              unsigned short* __restrict__ hhi,
                                              unsigned short* __restrict__ hlo,
                                              float* __restrict__ c)
{
    const int b = blockIdx.x; // 0..511
    for (int j = threadIdx.x; j < HH; j += 256) {
        float hv = (b < BB) ? h0a[b * HH + j] : h0b[(b - BB) * HH + j];
        float cv = (b < BB) ? c0a[b * HH + j] : c0b[(b - BB) * HH + j];
        unsigned short hi = f2bf(hv);
        hhi[b * HH + j] = hi;
        hlo[b * HH + j] = f2bf(hv - bf2f(hi));
        c[b * HH + j] = cv;
    }
}

// Pre-gather embeddings to bf16 (unchanged, verified).
__global__ __launch_bounds__(256) void gather_x(const int* __restrict__ s1,
                                                const int* __restrict__ s2,
                                                const float* __restrict__ emb,
                                                unsigned short* __restrict__ Xbf)
{
    const int idx = blockIdx.x * 256 + threadIdx.x;   // TT*BT*40 threads
    const int row = idx / 40;
    const int seg = idx - row * 40;
    const int t = row >> 9;
    const int b = row & 511;
    const int tok = (b < BB) ? s1[t * BB + b] : s2[t * BB + (b - BB)];
    const int k = seg * 8;
    short8v v;
    if (k + 8 <= DD) {
        const float* e0 = emb + (size_t)tok * DD + k;
        float4 va = *(const float4*)e0;
        float4 vb = *(const float4*)(e0 + 4);
        v[0] = (short)f2bf(va.x); v[1] = (short)f2bf(va.y);
        v[2] = (short)f2bf(va.z); v[3] = (short)f2bf(va.w);
        v[4] = (short)f2bf(vb.x); v[5] = (short)f2bf(vb.y);
        v[6] = (short)f2bf(vb.z); v[7] = (short)f2bf(vb.w);
    } else {
        #pragma unroll
        for (int e = 0; e < 8; ++e) {
            int c = k + e;
            v[e] = (c < DD) ? (short)f2bf(emb[(size_t)tok * DD + c]) : (short)0;
        }
    }
    *(short8v*)&Xbf[(size_t)row * KX + k] = v;
}

// ---------------------------------------------------------------------------
// xprojP[m][g''] GEMM (R8/R9/R10-verified, byte-identical): g''=jt*64+jj*4+grp.
__global__ __launch_bounds__(256) void gemm_x(
    const unsigned short* __restrict__ Xbf,
    const unsigned short* __restrict__ WihP,
    unsigned short* __restrict__ xprojP)
{
    __shared__ __align__(16) unsigned short As[64 * 64];
    __shared__ __align__(16) unsigned short Bs[64 * 64];
    __shared__ __align__(16) float gbuf[64 * 65];

    const int tid = threadIdx.x;
    const int xcd   = blockIdx.x & 7;
    const int local = blockIdx.x >> 3;
    const int mblk  = xcd * 64 + (local >> 5);
    const int nblk  = local & 31;

    const int lane = tid & 63;
    const int w = tid >> 6;
    const int wr = w >> 1, wc = w & 1;
    const int r16 = lane & 15;
    const int kg8 = lane >> 4;
    const int sl8 = lane >> 3;
    const int gd  = lane & 7;

    f32x4 acc[2][2] = {};

    auto load_chunk = [&](int ch, short8v* va, short8v* vb) {
        const int k0 = ch * KC;
        #pragma unroll
        for (int s = 0; s < 2; ++s) {
            const int r = w * 16 + s * 8 + sl8;
            va[s] = *(const short8v*)(Xbf + (size_t)(mblk * 64 + r) * KX + k0 + gd * 8);
            vb[s] = *(const short8v*)(WihP + (size_t)(nblk * 64 + r) * KX + k0 + gd * 8);
        }
    };
    auto write_chunk = [&](const short8v* va, const short8v* vb) {
        #pragma unroll
        for (int s = 0; s < 2; ++s) {
            const int r = w * 16 + s * 8 + sl8;
            const int g = (gd ^ sl8) << 3;
            *(short8v*)&As[r * 64 + g] = va[s];
            *(short8v*)&Bs[r * 64 + g] = vb[s];
        }
    };
    auto lidx = [&](int r, int ko) { return r * 64 + ((((ko) >> 3) ^ (r & 7)) << 3); };

    short8v va[2], vb[2], na[2], nb[2];
    load_chunk(0, va, vb);
    for (int ch = 0; ch < NCHX; ++ch) {
        write_chunk(va, vb);
        if (ch + 1 < NCHX) load_chunk(ch + 1, na, nb);
        __syncthreads();
        #pragma unroll
        for (int ks = 0; ks < KC; ks += 32) {
            const int ko = ks + kg8 * 8;
            short8v a0 = *(const short8v*)&As[lidx(32 * wr + r16,      ko)];
            short8v a1 = *(const short8v*)&As[lidx(32 * wr + 16 + r16, ko)];
            short8v b0 = *(const short8v*)&Bs[lidx(32 * wc + r16,      ko)];
            short8v b1 = *(const short8v*)&Bs[lidx(32 * wc + 16 + r16, ko)];
            acc[0][0] = __builtin_amdgcn_mfma_f32_16x16x32_bf16(a0, b0, acc[0][0], 0, 0, 0);
            acc[0][1] = __builtin_amdgcn_mfma_f32_16x16x32_bf16(a0, b1, acc[0][1], 0, 0, 0);
            acc[1][0] = __builtin_amdgcn_mfma_f32_16x16x32_bf16(a1, b0, acc[1][0], 0, 0, 0);
            acc[1][1] = __builtin_amdgcn_mfma_f32_16x16x32_bf16(a1, b1, acc[1][1], 0, 0, 0);
        }
        __syncthreads();
        #pragma unroll
        for (int s = 0; s < 2; ++s) { va[s] = na[s]; vb[s] = nb[s]; }
    }

    #pragma unroll
    for (int i = 0; i < 2; ++i)
        #pragma unroll
        for (int j = 0; j < 2; ++j)
            #pragma unroll
            for (int r = 0; r < 4; ++r) {
                int grow = (2 * wr + i) * 16 + kg8 * 4 + r;
                int gcol = (2 * wc + j) * 16 + r16;
                gbuf[grow * 65 + gcol] = acc[i][j][r];
            }
    __syncthreads();

    const int jj = tid & 15;
    const int row0 = tid >> 4;
    #pragma unroll
    for (int u = 0; u < 4; ++u) {
        int row = row0 + 16 * u;
        size_t m = (size_t)(mblk * 64 + row);
        ushort4v o;
        o[0] = f2bf(gbuf[row * 65 +      jj]);
        o[1] = f2bf(gbuf[row * 65 + 16 + jj]);
        o[2] = f2bf(gbuf[row * 65 + 32 + jj]);
        o[3] = f2bf(gbuf[row * 65 + 48 + jj]);
        __builtin_nontemporal_store(o, (ushort4v*)&xprojP[m * G4 + nblk * 64 + jj * 4]);
    }
}

// ---------------------------------------------------------------------------
// One LSTM timestep. Tile 64 batch x 32 g''-cols (8 j x 4 gates), 512 blocks
// x 128 threads (2 waves, 2 blocks/CU so barrier drains overlap). 2-term
// A-K = [h_hi | h_lo], B = W_hi re-read. 16 chunks, dbuf, XOR-swizzled LDS.
#define MF(a, b, c) __builtin_amdgcn_mfma_f32_16x16x32_bf16(a, b, c, 0, 0, 0)

__global__ __launch_bounds__(128) void lstm_step(
    const unsigned short* __restrict__ WcatP,
    const float* __restrict__ biasP,
    const unsigned short* __restrict__ xprojP,
    const unsigned short* __restrict__ hhi_in,
    const unsigned short* __restrict__ hlo_in,
    float* __restrict__ cbuf,
    unsigned short* __restrict__ hhi_out,
    unsigned short* __restrict__ hlo_out,
    int t)
{
    __shared__ __align__(16) unsigned short As0[64 * 64], As1[64 * 64]; // 8 KB each
    __shared__ __align__(16) unsigned short Bs0[32 * 64], Bs1[32 * 64]; // 4 KB each
    __shared__ __align__(16) float gbuf[64 * 36];                       // 9 KB

    const int tid = threadIdx.x;
    const int bid = blockIdx.x;
    const int xcd   = bid & 7;
    const int local = bid >> 3;           // 0..63
    const int ct    = xcd * 8 + (local & 7);  // col tile 0..63 (32 g'' cols each)
    const int bx    = local >> 3;             // batch block 0..7

    const int lane = tid & 63;
    const int w = tid >> 6;               // wave = row half
    const int r16 = lane & 15;
    const int kg8 = lane >> 4;

    // staging decode
    const int srowA = tid >> 1;           // 0..63, 2 thr/row, 4 granules each
    const int qA    = (tid & 1) * 4;
    const int srowB = tid >> 2;           // 0..31, 4 thr/row, 2 granules each
    const int qB    = (tid & 3) * 2;

    f32x4 acc[2][2] = {};

    auto load_chunk = [&](int ch, short8v* va, short8v* vb) {
        const int k0 = ch * KC;
        const unsigned short* abase = (k0 < HH)
            ? hhi_in + (size_t)(bx * 64) * HH + k0
            : hlo_in + (size_t)(bx * 64) * HH + (k0 - HH);
        const int kw = k0 & (HH - 1);     // W-hi slice re-read for lo half
        #pragma unroll
        for (int q = 0; q < 4; ++q)
            va[q] = *(const short8v*)(abase + (size_t)srowA * HH + (qA + q) * 8);
        #pragma unroll
        for (int q = 0; q < 2; ++q)
            vb[q] = *(const short8v*)(WcatP + (size_t)(ct * 32 + srowB) * KW + kw + (qB + q) * 8);
    };
    auto write_chunk = [&](unsigned short* A, unsigned short* B,
                           const short8v* va, const short8v* vb) {
        #pragma unroll
        for (int q = 0; q < 4; ++q) {
            const int g = ((qA + q) ^ (srowA & 7)) << 3;
            *(short8v*)&A[srowA * 64 + g] = va[q];
        }
        #pragma unroll
        for (int q = 0; q < 2; ++q) {
            const int g = ((qB + q) ^ (srowB & 7)) << 3;
            *(short8v*)&B[srowB * 64 + g] = vb[q];
        }
    };
    auto lidx = [&](int r, int ko) { return r * 64 + ((((ko) >> 3) ^ (r & 7)) << 3); };
    auto compute = [&](const unsigned short* A, const unsigned short* B) {
        #pragma unroll
        for (int ks = 0; ks < KC; ks += 32) {
            const int ko = ks + kg8 * 8;
            short8v a0 = *(const short8v*)&A[lidx(32 * w + r16,      ko)];
            short8v a1 = *(const short8v*)&A[lidx(32 * w + 16 + r16, ko)];
            short8v b0 = *(const short8v*)&B[lidx(r16,      ko)];
            short8v b1 = *(const short8v*)&B[lidx(16 + r16, ko)];
            acc[0][0] = MF(a0, b0, acc[0][0]);
            acc[0][1] = MF(a0, b1, acc[0][1]);
            acc[1][0] = MF(a1, b0, acc[1][0]);
            acc[1][1] = MF(a1, b1, acc[1][1]);
        }
    };

    short8v ra[4], rb[2], sa[4], sb[2];
    load_chunk(0, ra, rb);
    load_chunk(1, sa, sb);

    // epilogue prefetch (R9-verified indexing: jl 0..7, row0 0..15)
    const int jl   = tid & 7;
    const int row0 = tid >> 3;
    const int j    = ct * 8 + jl;
    const f32x4 bp = *(const f32x4*)&biasP[4 * j];
    ushort4v xp[4]; float cp[4];
    #pragma unroll
    for (int u = 0; u < 4; ++u) {
        int batch = bx * 64 + u * 16 + row0;
        xp[u] = __builtin_nontemporal_load(
            (const ushort4v*)&xprojP[((size_t)t * BT + batch) * G4 + 4 * j]);
        cp[u] = cbuf[batch * HH + j];
    }

    write_chunk(As0, Bs0, ra, rb);
    __syncthreads();

    for (int ch = 0; ch < NCHH; ch += 2) {
        if (ch + 2 < NCHH) load_chunk(ch + 2, ra, rb);
        write_chunk(As1, Bs1, sa, sb);       // chunk ch+1 (NCHH even)
        compute(As0, Bs0);                    // chunk ch
        __syncthreads();
        if (ch + 3 < NCHH) load_chunk(ch + 3, sa, sb);
        if (ch + 2 < NCHH) write_chunk(As0, Bs0, ra, rb);
        compute(As1, Bs1);                    // chunk ch+1
        __syncthreads();
    }

    // gate exchange (C/D: row=(lane>>4)*4+reg, col=lane&15; R9-verified)
    #pragma unroll
    for (int i = 0; i < 2; ++i)
        #pragma unroll
        for (int cb = 0; cb < 2; ++cb)
            #pragma unroll
            for (int r = 0; r < 4; ++r)
                gbuf[(w * 32 + i * 16 + kg8 * 4 + r) * 36 + cb * 16 + r16]
                    = acc[i][cb][r];
    __syncthreads();

    // cell update: 4 (b,j) pairs per thread, gates contiguous (g''=4j+gate)
    #pragma unroll
    for (int u = 0; u < 4; ++u) {
        int row = u * 16 + row0;
        int batch = bx * 64 + row;
        f32x4 gv = *(const f32x4*)&gbuf[row * 36 + jl * 4];
        float gi = gv[0] + bp[0] + bf2f(xp[u][0]);
        float gf = gv[1] + bp[1] + bf2f(xp[u][1]);
        float gg = gv[2] + bp[2] + bf2f(xp[u][2]);
        float go = gv[3] + bp[3] + bf2f(xp[u][3]);
        float cn = sigm(gf) * cp[u] + sigm(gi) * tanh_f(gg);
        float hn = sigm(go) * tanh_f(cn);
        cbuf[batch * HH + j] = cn;
        unsigned short hi = f2bf(hn);
        hhi_out[batch * HH + j] = hi;
        hlo_out[batch * HH + j] = f2bf(hn - bf2f(hi));
    }
}

// ---------------------------------------------------------------------------
__global__ __launch_bounds__(64) void finalize(const unsigned short* __restrict__ hhi,
                                               const unsigned short* __restrict__ hlo,
                                               float* __restrict__ out)
{
    const int b = blockIdx.x;       // 0..255
    const int lane = threadIdx.x;   // 64
    float s = 0.0f;
    for (int j = lane; j < HH; j += 64) {
        float ha = bf2f(hhi[b * HH + j]) + bf2f(hlo[b * HH + j]);
        float hb = bf2f(hhi[(b + BB) * HH + j]) + bf2f(hlo[(b + BB) * HH + j]);
        s += fabsf(ha - hb);
    }
    #pragma unroll
    for (int off = 32; off > 0; off >>= 1) s += __shfl_down(s, off);
    if (lane == 0) out[b] = expf(-s);
}

// ---------------------------------------------------------------------------
extern "C" void kernel_launch(void* const* d_in, const int* in_sizes, int n_in,
                              void* d_out, int out_size, void* d_ws, size_t ws_size,
                              hipStream_t stream)
{
    const int*   s1  = (const int*)d_in[0];
    const int*   s2  = (const int*)d_in[1];
    const float* emb = (const float*)d_in[2];
    const float* Wih = (const float*)d_in[3];
    const float* Whh = (const float*)d_in[4];
    const float* bih = (const float*)d_in[5];
    const float* bhh = (const float*)d_in[6];
    const float* h0a = (const float*)d_in[7];
    const float* c0a = (const float*)d_in[8];
    const float* h0b = (const float*)d_in[9];
    const float* c0b = (const float*)d_in[10];
    float* out = (float*)d_out;

    char* ws = (char*)d_ws;
    size_t off = 0;
    unsigned short* WcatP = (unsigned short*)(ws + off); off += (size_t)G4 * KW * 2;   // 2 MB
    unsigned short* WihP  = (unsigned short*)(ws + off); off += (size_t)G4 * KX * 2;   // 1.3 MB
    float* biasP          = (float*)(ws + off);          off += (size_t)G4 * 4;
    unsigned short* hhi0  = (unsigned short*)(ws + off); off += (size_t)BT * HH * 2;
    unsigned short* hhi1  = (unsigned short*)(ws + off); off += (size_t)BT * HH * 2;
    unsigned short* hlo0  = (unsigned short*)(ws + off); off += (size_t)BT * HH * 2;
    unsigned short* hlo1  = (unsigned short*)(ws + off); off += (size_t)BT * HH * 2;
    float* cbuf           = (float*)(ws + off);          off += (size_t)BT * HH * 4;   // 1 MB
    unsigned short* Xbf   = (unsigned short*)(ws + off); off += (size_t)TT * BT * KX * 2; // 21 MB
    unsigned short* xprojP= (unsigned short*)(ws + off); off += (size_t)TT * BT * G4 * 2; // 134 MB

    prep_w<<<G4, 256, 0, stream>>>(Wih, Whh, bih, bhh, WcatP, WihP, biasP);
    prep_h<<<BT, 256, 0, stream>>>(h0a, c0a, h0b, c0b, hhi0, hlo0, cbuf);
    gather_x<<<(TT * BT * 40) / 256, 256, 0, stream>>>(s1, s2, emb, Xbf);
    gemm_x<<<512 * 32, 256, 0, stream>>>(Xbf, WihP, xprojP);

    unsigned short* hhi[2] = { hhi0, hhi1 };
    unsigned short* hlo[2] = { hlo0, hlo1 };
    for (int t = 0; t < TT; ++t) {
        int pi = t & 1, po = pi ^ 1;
        lstm_step<<<512, 128, 0, stream>>>(WcatP, biasP, xprojP,
                                           hhi[pi], hlo[pi], cbuf,
                                           hhi[po], hlo[po], t);
    }
    // t=63 (odd) writes buffer 0
    finalize<<<BB, 64, 0, stream>>>(hhi0, hlo0, out);
}

// Round 12
// 695.438 us; speedup vs baseline: 1.0687x; 1.0687x over previous
//
#include <hip/hip_runtime.h>
#include <hip/hip_bf16.h>
#include <math.h>

// Problem constants
#define TT 64
#define BB 256      // per-sequence batch
#define BT 512      // total batch (both sequences)
#define DD 300      // embedding dim
#define HH 512      // hidden
#define G4 2048     // 4*H
#define KX 320      // padded x-region K
#define KW 512      // physical W-hi K (read twice: A = [h_hi | h_lo])
#define KC 64       // K sub-chunk (LDS stage granularity)
#define NCHX 5      // KX / KC (gemm_x)
#define KC2 128     // lstm_step macro-chunk
#define NCH2 8      // 1024 / KC2

typedef __attribute__((ext_vector_type(8))) short short8v;
typedef __attribute__((ext_vector_type(4))) float f32x4;
typedef __attribute__((ext_vector_type(4))) unsigned short ushort4v;

__device__ __forceinline__ unsigned short f2bf(float f) {
    union { float f; unsigned int u; } v; v.f = f;
    unsigned int u = v.u;
    u += 0x7fffu + ((u >> 16) & 1u);   // round-to-nearest-even
    return (unsigned short)(u >> 16);
}
__device__ __forceinline__ float bf2f(unsigned short s) {
    union { unsigned int u; float f; } v; v.u = ((unsigned int)s) << 16;
    return v.f;
}
__device__ __forceinline__ float sigm(float x) { return 1.0f / (1.0f + __expf(-x)); }
__device__ __forceinline__ float tanh_f(float x) {
    float ax = fabsf(x);
    if (ax > 15.0f) return (x > 0.0f) ? 1.0f : -1.0f;
    float e = __expf(2.0f * ax);
    float t = 1.0f - 2.0f / (e + 1.0f);
    return (x >= 0.0f) ? t : -t;
}

// ---------------------------------------------------------------------------
// Prep (R10-verified layouts):
//  WcatP[g'][KW]: g' = jt*64 + grp*16 + jj  <->  gate g = grp*512 + jt*16 + jj
//  WihP[g'][KX]: bf16 W_ih rows (zero-padded 300..319)
//  biasP[jt*64 + jj*4 + grp] = b_ih[g] + b_hh[g]
__global__ __launch_bounds__(256) void prep_w(const float* __restrict__ Wih,
                                              const float* __restrict__ Whh,
                                              const float* __restrict__ bih,
                                              const float* __restrict__ bhh,
                                              unsigned short* __restrict__ WcatP,
                                              unsigned short* __restrict__ WihP,
                                              float* __restrict__ biasP)
{
    const int gp = blockIdx.x;            // g' 0..2047
    const int jt = gp >> 6, r = gp & 63;
    const int grp = r >> 4, jj = r & 15;
    const int g = grp * 512 + jt * 16 + jj;

    for (int k = threadIdx.x; k < KW; k += 256)
        WcatP[(size_t)gp * KW + k] = f2bf(Whh[(size_t)g * HH + k]);
    for (int k = threadIdx.x; k < KX; k += 256)
        WihP[(size_t)gp * KX + k] = (k < DD) ? f2bf(Wih[(size_t)g * DD + k])
                                             : (unsigned short)0;
    if (threadIdx.x == 0) biasP[jt * 64 + jj * 4 + grp] = bih[g] + bhh[g];
}

// Prep: initial h (hi/lo bf16) and c.
__global__ __launch_bounds__(256) void prep_h(const float* __restrict__ h0a,
                                              const float* __restrict__ c0a,
                                              const float* __restrict__ h0b,
                                              const float* __restrict__ c0b,
                                              unsigned short* __restrict__ hhi,
                                              unsigned short* __restrict__ hlo,
                                              float* __restrict__ c)
{
    const int b = blockIdx.x; // 0..511
    for (int j = threadIdx.x; j < HH; j += 256) {
        float hv = (b < BB) ? h0a[b * HH + j] : h0b[(b - BB) * HH + j];
        float cv = (b < BB) ? c0a[b * HH + j] : c0b[(b - BB) * HH + j];
        unsigned short hi = f2bf(hv);
        hhi[b * HH + j] = hi;
        hlo[b * HH + j] = f2bf(hv - bf2f(hi));
        c[b * HH + j] = cv;
    }
}

// Pre-gather embeddings to bf16: Xbf[t*512+b][0..KX) (zero-padded past DD).
__global__ __launch_bounds__(256) void gather_x(const int* __restrict__ s1,
                                                const int* __restrict__ s2,
                                                const float* __restrict__ emb,
                                                unsigned short* __restrict__ Xbf)
{
    const int idx = blockIdx.x * 256 + threadIdx.x;   // TT*BT*40 threads
    const int row = idx / 40;          // t*512 + b
    const int seg = idx - row * 40;    // 8-elem segment within 320
    const int t = row >> 9;
    const int b = row & 511;
    const int tok = (b < BB) ? s1[t * BB + b] : s2[t * BB + (b - BB)];
    const int k = seg * 8;
    short8v v;
    if (k + 8 <= DD) {
        const float* e0 = emb + (size_t)tok * DD + k;
        float4 va = *(const float4*)e0;
        float4 vb = *(const float4*)(e0 + 4);
        v[0] = (short)f2bf(va.x); v[1] = (short)f2bf(va.y);
        v[2] = (short)f2bf(va.z); v[3] = (short)f2bf(va.w);
        v[4] = (short)f2bf(vb.x); v[5] = (short)f2bf(vb.y);
        v[6] = (short)f2bf(vb.z); v[7] = (short)f2bf(vb.w);
    } else {
        #pragma unroll
        for (int e = 0; e < 8; ++e) {
            int c = k + e;
            v[e] = (c < DD) ? (short)f2bf(emb[(size_t)tok * DD + c]) : (short)0;
        }
    }
    *(short8v*)&Xbf[(size_t)row * KX + k] = v;
}

// ---------------------------------------------------------------------------
// xprojP[m][g''] GEMM (R8/R9/R10-verified, byte-identical): g''=jt*64+jj*4+grp.
__global__ __launch_bounds__(256) void gemm_x(
    const unsigned short* __restrict__ Xbf,
    const unsigned short* __restrict__ WihP,
    unsigned short* __restrict__ xprojP)
{
    __shared__ __align__(16) unsigned short As[64 * 64];
    __shared__ __align__(16) unsigned short Bs[64 * 64];
    __shared__ __align__(16) float gbuf[64 * 65];

    const int tid = threadIdx.x;
    const int xcd   = blockIdx.x & 7;
    const int local = blockIdx.x >> 3;
    const int mblk  = xcd * 64 + (local >> 5);
    const int nblk  = local & 31;

    const int lane = tid & 63;
    const int w = tid >> 6;
    const int wr = w >> 1, wc = w & 1;
    const int r16 = lane & 15;
    const int kg8 = lane >> 4;
    const int sl8 = lane >> 3;
    const int gd  = lane & 7;

    f32x4 acc[2][2] = {};

    auto load_chunk = [&](int ch, short8v* va, short8v* vb) {
        const int k0 = ch * KC;
        #pragma unroll
        for (int s = 0; s < 2; ++s) {
            const int r = w * 16 + s * 8 + sl8;
            va[s] = *(const short8v*)(Xbf + (size_t)(mblk * 64 + r) * KX + k0 + gd * 8);
            vb[s] = *(const short8v*)(WihP + (size_t)(nblk * 64 + r) * KX + k0 + gd * 8);
        }
    };
    auto write_chunk = [&](const short8v* va, const short8v* vb) {
        #pragma unroll
        for (int s = 0; s < 2; ++s) {
            const int r = w * 16 + s * 8 + sl8;
            const int g = (gd ^ sl8) << 3;
            *(short8v*)&As[r * 64 + g] = va[s];
            *(short8v*)&Bs[r * 64 + g] = vb[s];
        }
    };
    auto lidx = [&](int r, int ko) { return r * 64 + ((((ko) >> 3) ^ (r & 7)) << 3); };

    short8v va[2], vb[2], na[2], nb[2];
    load_chunk(0, va, vb);
    for (int ch = 0; ch < NCHX; ++ch) {
        write_chunk(va, vb);
        if (ch + 1 < NCHX) load_chunk(ch + 1, na, nb);
        __syncthreads();
        #pragma unroll
        for (int ks = 0; ks < KC; ks += 32) {
            const int ko = ks + kg8 * 8;
            short8v a0 = *(const short8v*)&As[lidx(32 * wr + r16,      ko)];
            short8v a1 = *(const short8v*)&As[lidx(32 * wr + 16 + r16, ko)];
            short8v b0 = *(const short8v*)&Bs[lidx(32 * wc + r16,      ko)];
            short8v b1 = *(const short8v*)&Bs[lidx(32 * wc + 16 + r16, ko)];
            acc[0][0] = __builtin_amdgcn_mfma_f32_16x16x32_bf16(a0, b0, acc[0][0], 0, 0, 0);
            acc[0][1] = __builtin_amdgcn_mfma_f32_16x16x32_bf16(a0, b1, acc[0][1], 0, 0, 0);
            acc[1][0] = __builtin_amdgcn_mfma_f32_16x16x32_bf16(a1, b0, acc[1][0], 0, 0, 0);
            acc[1][1] = __builtin_amdgcn_mfma_f32_16x16x32_bf16(a1, b1, acc[1][1], 0, 0, 0);
        }
        __syncthreads();
        #pragma unroll
        for (int s = 0; s < 2; ++s) { va[s] = na[s]; vb[s] = nb[s]; }
    }

    #pragma unroll
    for (int i = 0; i < 2; ++i)
        #pragma unroll
        for (int j = 0; j < 2; ++j)
            #pragma unroll
            for (int r = 0; r < 4; ++r) {
                int grow = (2 * wr + i) * 16 + kg8 * 4 + r;
                int gcol = (2 * wc + j) * 16 + r16;
                gbuf[grow * 65 + gcol] = acc[i][j][r];
            }
    __syncthreads();

    const int jj = tid & 15;
    const int row0 = tid >> 4;
    #pragma unroll
    for (int u = 0; u < 4; ++u) {
        int row = row0 + 16 * u;
        size_t m = (size_t)(mblk * 64 + row);
        ushort4v o;
        o[0] = f2bf(gbuf[row * 65 +      jj]);
        o[1] = f2bf(gbuf[row * 65 + 16 + jj]);
        o[2] = f2bf(gbuf[row * 65 + 32 + jj]);
        o[3] = f2bf(gbuf[row * 65 + 48 + jj]);
        __builtin_nontemporal_store(o, (ushort4v*)&xprojP[m * G4 + nblk * 64 + jj * 4]);
    }
}

// ---------------------------------------------------------------------------
// One LSTM timestep (R10-verified algebra). Macro-chunks of KC2=128 staged as
// two verbatim R10 sub-chunks into 128-row LDS buffers -> 9 barriers instead
// of 17. Tile 64 batch x 64 gate-cols, 256 blocks x 256 threads.
__global__ __launch_bounds__(256) void lstm_step(
    const unsigned short* __restrict__ WcatP,
    const float* __restrict__ biasP,
    const unsigned short* __restrict__ xprojP,
    const unsigned short* __restrict__ hhi_in,
    const unsigned short* __restrict__ hlo_in,
    float* __restrict__ cbuf,
    unsigned short* __restrict__ hhi_out,
    unsigned short* __restrict__ hlo_out,
    int t)
{
    // 64 KB static LDS: A0|A1|B0|B1, each 128x64 shorts (16 KB).
    __shared__ __align__(16) unsigned short smem[4 * 128 * 64];
    unsigned short* const Abuf[2] = { smem, smem + 8192 };
    unsigned short* const Bbuf[2] = { smem + 16384, smem + 24576 };

    const int tid = threadIdx.x;
    const int bid = blockIdx.x;

    // XCD-aware decode: each XCD owns 4 contiguous jt tiles.
    const int xcd   = bid & 7;
    const int local = bid >> 3;
    const int bx    = local & 7;
    const int jt    = xcd * 4 + (local >> 3);

    const int lane = tid & 63;
    const int w = tid >> 6;
    const int wr = w >> 1, wc = w & 1;
    const int r16 = lane & 15;
    const int kg8 = lane >> 4;
    const int sl8 = lane >> 3;
    const int gd  = lane & 7;

    f32x4 acc[2][2] = {};

    // Macro-chunk = 2 sub-chunks of 64; each sub-chunk uses R10's exact
    // row/granule/swizzle staging, at LDS row offset sub*64.
    auto load_chunk = [&](int ch, short8v* va, short8v* vb) {
        #pragma unroll
        for (int sub = 0; sub < 2; ++sub) {
            const int k0 = ch * KC2 + sub * KC;
            const unsigned short* abase = (k0 < HH)
                ? hhi_in + (size_t)(bx * 64) * HH + k0
                : hlo_in + (size_t)(bx * 64) * HH + (k0 - HH);
            const int kw = k0 & (HH - 1);
            #pragma unroll
            for (int s = 0; s < 2; ++s) {
                const int r = w * 16 + s * 8 + sl8;
                va[sub * 2 + s] = *(const short8v*)(abase + (size_t)r * HH + gd * 8);
                vb[sub * 2 + s] = *(const short8v*)(WcatP + (size_t)(jt * 64 + r) * KW + kw + gd * 8);
            }
        }
    };
    auto write_chunk = [&](unsigned short* A, unsigned short* B,
                           const short8v* va, const short8v* vb) {
        #pragma unroll
        for (int sub = 0; sub < 2; ++sub)
            #pragma unroll
            for (int s = 0; s < 2; ++s) {
                const int r = w * 16 + s * 8 + sl8;
                const int g = (gd ^ sl8) << 3;     // r&7 == sl8
                *(short8v*)&A[(sub * 64 + r) * 64 + g] = va[sub * 2 + s];
                *(short8v*)&B[(sub * 64 + r) * 64 + g] = vb[sub * 2 + s];
            }
    };
    auto lidx = [&](int r, int ko) { return r * 64 + ((((ko) >> 3) ^ (r & 7)) << 3); };
    auto compute = [&](const unsigned short* A, const unsigned short* B) {
        #pragma unroll
        for (int sub = 0; sub < 2; ++sub)
            #pragma unroll
            for (int ks = 0; ks < KC; ks += 32) {
                const int ko = ks + kg8 * 8;
                const int ro = sub * 64;
                short8v a0 = *(const short8v*)&A[lidx(ro + 32 * wr + r16,      ko)];
                short8v a1 = *(const short8v*)&A[lidx(ro + 32 * wr + 16 + r16, ko)];
                short8v b0 = *(const short8v*)&B[lidx(ro + 32 * wc + r16,      ko)];
                short8v b1 = *(const short8v*)&B[lidx(ro + 32 * wc + 16 + r16, ko)];
                acc[0][0] = __builtin_amdgcn_mfma_f32_16x16x32_bf16(a0, b0, acc[0][0], 0, 0, 0);
                acc[0][1] = __builtin_amdgcn_mfma_f32_16x16x32_bf16(a0, b1, acc[0][1], 0, 0, 0);
                acc[1][0] = __builtin_amdgcn_mfma_f32_16x16x32_bf16(a1, b0, acc[1][0], 0, 0, 0);
                acc[1][1] = __builtin_amdgcn_mfma_f32_16x16x32_bf16(a1, b1, acc[1][1], 0, 0, 0);
            }
    };

    short8v ra[4], rb[4], sa[4], sb[4];
    load_chunk(0, ra, rb);
    load_chunk(1, sa, sb);

    // epilogue prefetch
    const int jj = tid & 15;
    const int row0 = tid >> 4;
    const f32x4 bp = *(const f32x4*)&biasP[jt * 64 + jj * 4];
    ushort4v xp[4]; float cp[4];
    #pragma unroll
    for (int u = 0; u < 4; ++u) {
        int batch = bx * 64 + row0 + 16 * u;
        xp[u] = __builtin_nontemporal_load(
            (const ushort4v*)&xprojP[((size_t)t * BT + batch) * G4 + jt * 64 + jj * 4]);
        cp[u] = cbuf[batch * HH + jt * 16 + jj];
    }

    write_chunk(Abuf[0], Bbuf[0], ra, rb);
    __syncthreads();

    for (int ch = 0; ch < NCH2; ch += 2) {
        if (ch + 2 < NCH2) load_chunk(ch + 2, ra, rb);
        write_chunk(Abuf[1], Bbuf[1], sa, sb);   // chunk ch+1 (NCH2 even)
        compute(Abuf[0], Bbuf[0]);                // chunk ch
        __syncthreads();
        if (ch + 3 < NCH2) load_chunk(ch + 3, sa, sb);
        if (ch + 2 < NCH2) write_chunk(Abuf[0], Bbuf[0], ra, rb);
        compute(Abuf[1], Bbuf[1]);                // chunk ch+1
        __syncthreads();
    }

    // gate exchange (C/D: row=(lane>>4)*4+reg, col=lane&15; verified).
    // gbuf aliases smem — all K-loop LDS reads completed at the last barrier.
    float* gbuf = (float*)smem;   // 64 x 65 floats = 16.6 KB
    #pragma unroll
    for (int i = 0; i < 2; ++i)
        #pragma unroll
        for (int j2 = 0; j2 < 2; ++j2)
            #pragma unroll
            for (int r = 0; r < 4; ++r) {
                int grow = (2 * wr + i) * 16 + kg8 * 4 + r;
                int gcol = (2 * wc + j2) * 16 + r16;
                gbuf[grow * 65 + gcol] = acc[i][j2][r];
            }
    __syncthreads();

    #pragma unroll
    for (int u = 0; u < 4; ++u) {
        int row = row0 + 16 * u;
        int batch = bx * 64 + row;
        int j = jt * 16 + jj;
        float gi = gbuf[row * 65 +      jj] + bp[0] + bf2f(xp[u][0]);
        float gf = gbuf[row * 65 + 16 + jj] + bp[1] + bf2f(xp[u][1]);
        float gg = gbuf[row * 65 + 32 + jj] + bp[2] + bf2f(xp[u][2]);
        float go = gbuf[row * 65 + 48 + jj] + bp[3] + bf2f(xp[u][3]);
        float cn = sigm(gf) * cp[u] + sigm(gi) * tanh_f(gg);
        float hn = sigm(go) * tanh_f(cn);
        cbuf[batch * HH + j] = cn;
        unsigned short hi = f2bf(hn);
        hhi_out[batch * HH + j] = hi;
        hlo_out[batch * HH + j] = f2bf(hn - bf2f(hi));
    }
}

// ---------------------------------------------------------------------------
__global__ __launch_bounds__(64) void finalize(const unsigned short* __restrict__ hhi,
                                               const unsigned short* __restrict__ hlo,
                                               float* __restrict__ out)
{
    const int b = blockIdx.x;       // 0..255
    const int lane = threadIdx.x;   // 64
    float s = 0.0f;
    for (int j = lane; j < HH; j += 64) {
        float ha = bf2f(hhi[b * HH + j]) + bf2f(hlo[b * HH + j]);
        float hb = bf2f(hhi[(b + BB) * HH + j]) + bf2f(hlo[(b + BB) * HH + j]);
        s += fabsf(ha - hb);
    }
    #pragma unroll
    for (int off = 32; off > 0; off >>= 1) s += __shfl_down(s, off);
    if (lane == 0) out[b] = expf(-s);
}

// ---------------------------------------------------------------------------
extern "C" void kernel_launch(void* const* d_in, const int* in_sizes, int n_in,
                              void* d_out, int out_size, void* d_ws, size_t ws_size,
                              hipStream_t stream)
{
    const int*   s1  = (const int*)d_in[0];
    const int*   s2  = (const int*)d_in[1];
    const float* emb = (const float*)d_in[2];
    const float* Wih = (const float*)d_in[3];
    const float* Whh = (const float*)d_in[4];
    const float* bih = (const float*)d_in[5];
    const float* bhh = (const float*)d_in[6];
    const float* h0a = (const float*)d_in[7];
    const float* c0a = (const float*)d_in[8];
    const float* h0b = (const float*)d_in[9];
    const float* c0b = (const float*)d_in[10];
    float* out = (float*)d_out;

    char* ws = (char*)d_ws;
    size_t off = 0;
    unsigned short* WcatP = (unsigned short*)(ws + off); off += (size_t)G4 * KW * 2;   // 2 MB
    unsigned short* WihP  = (unsigned short*)(ws + off); off += (size_t)G4 * KX * 2;   // 1.3 MB
    float* biasP          = (float*)(ws + off);          off += (size_t)G4 * 4;
    unsigned short* hhi0  = (unsigned short*)(ws + off); off += (size_t)BT * HH * 2;
    unsigned short* hhi1  = (unsigned short*)(ws + off); off += (size_t)BT * HH * 2;
    unsigned short* hlo0  = (unsigned short*)(ws + off); off += (size_t)BT * HH * 2;
    unsigned short* hlo1  = (unsigned short*)(ws + off); off += (size_t)BT * HH * 2;
    float* cbuf           = (float*)(ws + off);          off += (size_t)BT * HH * 4;   // 1 MB
    unsigned short* Xbf   = (unsigned short*)(ws + off); off += (size_t)TT * BT * KX * 2; // 21 MB
    unsigned short* xprojP= (unsigned short*)(ws + off); off += (size_t)TT * BT * G4 * 2; // 134 MB

    prep_w<<<G4, 256, 0, stream>>>(Wih, Whh, bih, bhh, WcatP, WihP, biasP);
    prep_h<<<BT, 256, 0, stream>>>(h0a, c0a, h0b, c0b, hhi0, hlo0, cbuf);
    gather_x<<<(TT * BT * 40) / 256, 256, 0, stream>>>(s1, s2, emb, Xbf);
    gemm_x<<<512 * 32, 256, 0, stream>>>(Xbf, WihP, xprojP);

    unsigned short* hhi[2] = { hhi0, hhi1 };
    unsigned short* hlo[2] = { hlo0, hlo1 };
    for (int t = 0; t < TT; ++t) {
        int pi = t & 1, po = pi ^ 1;
        lstm_step<<<256, 256, 0, stream>>>(WcatP, biasP, xprojP,
                                           hhi[pi], hlo[pi], cbuf,
                                           hhi[po], hlo[po], t);
    }
    // t=63 (odd) writes buffer 0
    finalize<<<BB, 64, 0, stream>>>(hhi0, hlo0, out);
}

// Round 13
// 628.262 us; speedup vs baseline: 1.1829x; 1.1069x over previous
//
#include <hip/hip_runtime.h>
#include <hip/hip_bf16.h>
#include <math.h>

// Problem constants
#define TT 64
#define BB 256      // per-sequence batch
#define BT 512      // total batch (both sequences)
#define DD 300      // embedding dim
#define HH 512      // hidden
#define G4 2048     // 4*H
#define KX 320      // padded x-region K
#define KW 512      // physical W-hi K (read twice: A = [h_hi | h_lo])
#define KC 64       // K chunk per LDS stage
#define NCHX 5      // KX / KC
#define NCHH 16     // 1024 / KC (2-term: hi*Whi + lo*Whi)

typedef __attribute__((ext_vector_type(8))) short short8v;
typedef __attribute__((ext_vector_type(4))) float f32x4;
typedef __attribute__((ext_vector_type(4))) unsigned short ushort4v;

__device__ __forceinline__ unsigned short f2bf(float f) {
    union { float f; unsigned int u; } v; v.f = f;
    unsigned int u = v.u;
    u += 0x7fffu + ((u >> 16) & 1u);   // round-to-nearest-even
    return (unsigned short)(u >> 16);
}
__device__ __forceinline__ float bf2f(unsigned short s) {
    union { unsigned int u; float f; } v; v.u = ((unsigned int)s) << 16;
    return v.f;
}
__device__ __forceinline__ float sigm(float x) { return 1.0f / (1.0f + __expf(-x)); }
__device__ __forceinline__ float tanh_f(float x) {
    float ax = fabsf(x);
    if (ax > 15.0f) return (x > 0.0f) ? 1.0f : -1.0f;
    float e = __expf(2.0f * ax);
    float t = 1.0f - 2.0f / (e + 1.0f);
    return (x >= 0.0f) ? t : -t;
}

// ---------------------------------------------------------------------------
// Prep (R10-verified layouts):
//  WcatP[g'][KW]: g' = jt*64 + grp*16 + jj  <->  gate g = grp*512 + jt*16 + jj
//  WihP[g'][KX]: bf16 W_ih rows (zero-padded 300..319)
//  biasP[jt*64 + jj*4 + grp] = b_ih[g] + b_hh[g]
__global__ __launch_bounds__(256) void prep_w(const float* __restrict__ Wih,
                                              const float* __restrict__ Whh,
                                              const float* __restrict__ bih,
                                              const float* __restrict__ bhh,
                                              unsigned short* __restrict__ WcatP,
                                              unsigned short* __restrict__ WihP,
                                              float* __restrict__ biasP)
{
    const int gp = blockIdx.x;            // g' 0..2047
    const int jt = gp >> 6, r = gp & 63;
    const int grp = r >> 4, jj = r & 15;
    const int g = grp * 512 + jt * 16 + jj;

    for (int k = threadIdx.x; k < KW; k += 256)
        WcatP[(size_t)gp * KW + k] = f2bf(Whh[(size_t)g * HH + k]);
    for (int k = threadIdx.x; k < KX; k += 256)
        WihP[(size_t)gp * KX + k] = (k < DD) ? f2bf(Wih[(size_t)g * DD + k])
                                             : (unsigned short)0;
    if (threadIdx.x == 0) biasP[jt * 64 + jj * 4 + grp] = bih[g] + bhh[g];
}

// Prep: initial h (hi/lo bf16) and c.
__global__ __launch_bounds__(256) void prep_h(const float* __restrict__ h0a,
                                              const float* __restrict__ c0a,
                                              const float* __restrict__ h0b,
                                              const float* __restrict__ c0b,
                                              unsigned short* __restrict__ hhi,
                                              unsigned short* __restrict__ hlo,
                                              float* __restrict__ c)
{
    const int b = blockIdx.x; // 0..511
    for (int j = threadIdx.x; j < HH; j += 256) {
        float hv = (b < BB) ? h0a[b * HH + j] : h0b[(b - BB) * HH + j];
        float cv = (b < BB) ? c0a[b * HH + j] : c0b[(b - BB) * HH + j];
        unsigned short hi = f2bf(hv);
        hhi[b * HH + j] = hi;
        hlo[b * HH + j] = f2bf(hv - bf2f(hi));
        c[b * HH + j] = cv;
    }
}

// Pre-gather embeddings to bf16: Xbf[t*512+b][0..KX) (zero-padded past DD).
__global__ __launch_bounds__(256) void gather_x(const int* __restrict__ s1,
                                                const int* __restrict__ s2,
                                                const float* __restrict__ emb,
                                                unsigned short* __restrict__ Xbf)
{
    const int idx = blockIdx.x * 256 + threadIdx.x;   // TT*BT*40 threads
    const int row = idx / 40;          // t*512 + b
    const int seg = idx - row * 40;    // 8-elem segment within 320
    const int t = row >> 9;
    const int b = row & 511;
    const int tok = (b < BB) ? s1[t * BB + b] : s2[t * BB + (b - BB)];
    const int k = seg * 8;
    short8v v;
    if (k + 8 <= DD) {
        const float* e0 = emb + (size_t)tok * DD + k;
        float4 va = *(const float4*)e0;
        float4 vb = *(const float4*)(e0 + 4);
        v[0] = (short)f2bf(va.x); v[1] = (short)f2bf(va.y);
        v[2] = (short)f2bf(va.z); v[3] = (short)f2bf(va.w);
        v[4] = (short)f2bf(vb.x); v[5] = (short)f2bf(vb.y);
        v[6] = (short)f2bf(vb.z); v[7] = (short)f2bf(vb.w);
    } else {
        #pragma unroll
        for (int e = 0; e < 8; ++e) {
            int c = k + e;
            v[e] = (c < DD) ? (short)f2bf(emb[(size_t)tok * DD + c]) : (short)0;
        }
    }
    *(short8v*)&Xbf[(size_t)row * KX + k] = v;
}

// ---------------------------------------------------------------------------
// xprojP[m][g''] GEMM, 128x128 tile, 512 threads (8 waves = 2 row-halves x
// 4 col-quarters). Same verified swizzle algebra as the 64-tile version.
// Output layout identical: g'' = jt*64 + jj*4 + grp. nt stores.
__global__ __launch_bounds__(512) void gemm_x(
    const unsigned short* __restrict__ Xbf,
    const unsigned short* __restrict__ WihP,
    unsigned short* __restrict__ xprojP)
{
    // As (128x64) | Bs (128x64) shorts = 32 KB; gbuf (64x132 f32 = 33792 B)
    // aliases the same memory after the K loop.
    __shared__ __align__(16) unsigned short smem[16896];
    unsigned short* const As = smem;
    unsigned short* const Bs = smem + 8192;

    const int tid = threadIdx.x;
    const int xcd   = blockIdx.x & 7;
    const int local = blockIdx.x >> 3;        // 0..511
    const int mblk  = xcd * 32 + (local >> 4); // 0..255 (32 m-tiles per XCD)
    const int nblk  = local & 15;              // 0..15

    const int lane = tid & 63;
    const int wv  = tid >> 6;            // 0..7
    const int wr2 = wv >> 2;             // row half 0..1
    const int wc4 = wv & 3;              // col quarter 0..3
    const int r16 = lane & 15;
    const int kg8 = lane >> 4;

    // staging: 4 threads/row, 2 granules (16 shorts) each
    const int srow = tid >> 2;           // 0..127
    const int q2   = (tid & 3) * 2;      // source granule base

    f32x4 acc[4][2] = {};

    auto load_chunk = [&](int ch, short8v* va, short8v* vb) {
        const int k0 = ch * KC;
        #pragma unroll
        for (int e = 0; e < 2; ++e) {
            va[e] = *(const short8v*)(Xbf + (size_t)(mblk * 128 + srow) * KX + k0 + (q2 + e) * 8);
            vb[e] = *(const short8v*)(WihP + (size_t)(nblk * 128 + srow) * KX + k0 + (q2 + e) * 8);
        }
    };
    auto write_chunk = [&](const short8v* va, const short8v* vb) {
        #pragma unroll
        for (int e = 0; e < 2; ++e) {
            const int g = ((q2 + e) ^ (srow & 7)) << 3;
            *(short8v*)&As[srow * 64 + g] = va[e];
            *(short8v*)&Bs[srow * 64 + g] = vb[e];
        }
    };
    auto lidx = [&](int r, int ko) { return r * 64 + ((((ko) >> 3) ^ (r & 7)) << 3); };

    short8v va[2], vb[2], na[2], nb[2];
    load_chunk(0, va, vb);
    for (int ch = 0; ch < NCHX; ++ch) {
        write_chunk(va, vb);
        if (ch + 1 < NCHX) load_chunk(ch + 1, na, nb);
        __syncthreads();
        #pragma unroll
        for (int ks = 0; ks < KC; ks += 32) {
            const int ko = ks + kg8 * 8;
            short8v a[4], b[2];
            #pragma unroll
            for (int i = 0; i < 4; ++i)
                a[i] = *(const short8v*)&As[lidx(64 * wr2 + 16 * i + r16, ko)];
            #pragma unroll
            for (int j = 0; j < 2; ++j)
                b[j] = *(const short8v*)&Bs[lidx(32 * wc4 + 16 * j + r16, ko)];
            #pragma unroll
            for (int i = 0; i < 4; ++i)
                #pragma unroll
                for (int j = 0; j < 2; ++j)
                    acc[i][j] = __builtin_amdgcn_mfma_f32_16x16x32_bf16(a[i], b[j], acc[i][j], 0, 0, 0);
        }
        __syncthreads();
        #pragma unroll
        for (int e = 0; e < 2; ++e) { va[e] = na[e]; vb[e] = nb[e]; }
    }

    // Two-pass epilogue: pass p exchanges rows 64p..64p+63 through gbuf.
    float* gbuf = (float*)smem;          // 64 x 132 floats
    const int jj5 = tid & 31;            // h(0..1) x jj(0..15)
    const int hh  = jj5 >> 4;
    const int jj  = jj5 & 15;
    const int row0 = tid >> 5;           // 0..15
    #pragma unroll
    for (int p = 0; p < 2; ++p) {
        if (p) __syncthreads();          // pass-0 reads done before overwrite
        if (wr2 == p) {
            #pragma unroll
            for (int i = 0; i < 4; ++i)
                #pragma unroll
                for (int j = 0; j < 2; ++j)
                    #pragma unroll
                    for (int r = 0; r < 4; ++r)
                        gbuf[(16 * i + 4 * kg8 + r) * 132 + 32 * wc4 + 16 * j + r16]
                            = acc[i][j][r];
        }
        __syncthreads();
        #pragma unroll
        for (int u = 0; u < 4; ++u) {
            const int row = row0 + 16 * u;                 // 0..63 within pass
            const size_t m = (size_t)(mblk * 128 + p * 64 + row);
            ushort4v o;
            #pragma unroll
            for (int grp = 0; grp < 4; ++grp)
                o[grp] = f2bf(gbuf[row * 132 + hh * 64 + grp * 16 + jj]);
            __builtin_nontemporal_store(o,
                (ushort4v*)&xprojP[m * G4 + (nblk * 2 + hh) * 64 + jj * 4]);
        }
    }
}

// ---------------------------------------------------------------------------
// One LSTM timestep (R10-verified, byte-identical). 2-term: A-K = [h_hi|h_lo],
// B = W_hi re-read. 16 chunks of KC=64, dbuf LDS, 64x64 tile, 256 blocks.
__global__ __launch_bounds__(256) void lstm_step(
    const unsigned short* __restrict__ WcatP,
    const float* __restrict__ biasP,
    const unsigned short* __restrict__ xprojP,
    const unsigned short* __restrict__ hhi_in,
    const unsigned short* __restrict__ hlo_in,
    float* __restrict__ cbuf,
    unsigned short* __restrict__ hhi_out,
    unsigned short* __restrict__ hlo_out,
    int t)
{
    __shared__ __align__(16) unsigned short As0[64 * 64], As1[64 * 64];
    __shared__ __align__(16) unsigned short Bs0[64 * 64], Bs1[64 * 64];
    __shared__ __align__(16) float gbuf[64 * 65];

    const int tid = threadIdx.x;
    const int bid = blockIdx.x;

    // XCD-aware decode: each XCD owns 4 contiguous jt tiles.
    const int xcd   = bid & 7;
    const int local = bid >> 3;
    const int bx    = local & 7;
    const int jt    = xcd * 4 + (local >> 3);

    const int lane = tid & 63;
    const int w = tid >> 6;
    const int wr = w >> 1, wc = w & 1;
    const int r16 = lane & 15;
    const int kg8 = lane >> 4;
    const int sl8 = lane >> 3;
    const int gd  = lane & 7;

    f32x4 acc[2][2] = {};

    auto load_chunk = [&](int ch, short8v* va, short8v* vb) {
        const int k0 = ch * KC;
        const unsigned short* abase = (k0 < HH)
            ? hhi_in + (size_t)(bx * 64) * HH + k0
            : hlo_in + (size_t)(bx * 64) * HH + (k0 - HH);
        const int kw = k0 & (HH - 1);      // W-hi slice re-read for lo half
        #pragma unroll
        for (int s = 0; s < 2; ++s) {
            const int r = w * 16 + s * 8 + sl8;
            va[s] = *(const short8v*)(abase + (size_t)r * HH + gd * 8);
            vb[s] = *(const short8v*)(WcatP + (size_t)(jt * 64 + r) * KW + kw + gd * 8);
        }
    };
    auto write_chunk = [&](unsigned short* A, unsigned short* B,
                           const short8v* va, const short8v* vb) {
        #pragma unroll
        for (int s = 0; s < 2; ++s) {
            const int r = w * 16 + s * 8 + sl8;
            const int g = (gd ^ sl8) << 3;     // r&7 == sl8
            *(short8v*)&A[r * 64 + g] = va[s];
            *(short8v*)&B[r * 64 + g] = vb[s];
        }
    };
    auto lidx = [&](int r, int ko) { return r * 64 + ((((ko) >> 3) ^ (r & 7)) << 3); };
    auto compute = [&](const unsigned short* A, const unsigned short* B) {
        #pragma unroll
        for (int ks = 0; ks < KC; ks += 32) {
            const int ko = ks + kg8 * 8;
            short8v a0 = *(const short8v*)&A[lidx(32 * wr + r16,      ko)];
            short8v a1 = *(const short8v*)&A[lidx(32 * wr + 16 + r16, ko)];
            short8v b0 = *(const short8v*)&B[lidx(32 * wc + r16,      ko)];
            short8v b1 = *(const short8v*)&B[lidx(32 * wc + 16 + r16, ko)];
            acc[0][0] = __builtin_amdgcn_mfma_f32_16x16x32_bf16(a0, b0, acc[0][0], 0, 0, 0);
            acc[0][1] = __builtin_amdgcn_mfma_f32_16x16x32_bf16(a0, b1, acc[0][1], 0, 0, 0);
            acc[1][0] = __builtin_amdgcn_mfma_f32_16x16x32_bf16(a1, b0, acc[1][0], 0, 0, 0);
            acc[1][1] = __builtin_amdgcn_mfma_f32_16x16x32_bf16(a1, b1, acc[1][1], 0, 0, 0);
        }
    };

    short8v ra[2], rb[2], sa[2], sb[2];
    load_chunk(0, ra, rb);
    load_chunk(1, sa, sb);

    // epilogue prefetch
    const int jj = tid & 15;
    const int row0 = tid >> 4;
    const f32x4 bp = *(const f32x4*)&biasP[jt * 64 + jj * 4];
    ushort4v xp[4]; float cp[4];
    #pragma unroll
    for (int u = 0; u < 4; ++u) {
        int batch = bx * 64 + row0 + 16 * u;
        xp[u] = __builtin_nontemporal_load(
            (const ushort4v*)&xprojP[((size_t)t * BT + batch) * G4 + jt * 64 + jj * 4]);
        cp[u] = cbuf[batch * HH + jt * 16 + jj];
    }

    write_chunk(As0, Bs0, ra, rb);
    __syncthreads();

    for (int ch = 0; ch < NCHH; ch += 2) {
        if (ch + 2 < NCHH) load_chunk(ch + 2, ra, rb);
        write_chunk(As1, Bs1, sa, sb);       // chunk ch+1 (NCHH even)
        compute(As0, Bs0);                    // chunk ch
        __syncthreads();
        if (ch + 3 < NCHH) load_chunk(ch + 3, sa, sb);
        if (ch + 2 < NCHH) write_chunk(As0, Bs0, ra, rb);
        compute(As1, Bs1);                    // chunk ch+1
        __syncthreads();
    }

    // gate exchange (verified C/D mapping: row=(lane>>4)*4+reg, col=lane&15)
    #pragma unroll
    for (int i = 0; i < 2; ++i)
        #pragma unroll
        for (int j2 = 0; j2 < 2; ++j2)
            #pragma unroll
            for (int r = 0; r < 4; ++r) {
                int grow = (2 * wr + i) * 16 + kg8 * 4 + r;
                int gcol = (2 * wc + j2) * 16 + r16;
                gbuf[grow * 65 + gcol] = acc[i][j2][r];
            }
    __syncthreads();

    #pragma unroll
    for (int u = 0; u < 4; ++u) {
        int row = row0 + 16 * u;
        int batch = bx * 64 + row;
        int j = jt * 16 + jj;
        float gi = gbuf[row * 65 +      jj] + bp[0] + bf2f(xp[u][0]);
        float gf = gbuf[row * 65 + 16 + jj] + bp[1] + bf2f(xp[u][1]);
        float gg = gbuf[row * 65 + 32 + jj] + bp[2] + bf2f(xp[u][2]);
        float go = gbuf[row * 65 + 48 + jj] + bp[3] + bf2f(xp[u][3]);
        float cn = sigm(gf) * cp[u] + sigm(gi) * tanh_f(gg);
        float hn = sigm(go) * tanh_f(cn);
        cbuf[batch * HH + j] = cn;
        unsigned short hi = f2bf(hn);
        hhi_out[batch * HH + j] = hi;
        hlo_out[batch * HH + j] = f2bf(hn - bf2f(hi));
    }
}

// ---------------------------------------------------------------------------
__global__ __launch_bounds__(64) void finalize(const unsigned short* __restrict__ hhi,
                                               const unsigned short* __restrict__ hlo,
                                               float* __restrict__ out)
{
    const int b = blockIdx.x;       // 0..255
    const int lane = threadIdx.x;   // 64
    float s = 0.0f;
    for (int j = lane; j < HH; j += 64) {
        float ha = bf2f(hhi[b * HH + j]) + bf2f(hlo[b * HH + j]);
        float hb = bf2f(hhi[(b + BB) * HH + j]) + bf2f(hlo[(b + BB) * HH + j]);
        s += fabsf(ha - hb);
    }
    #pragma unroll
    for (int off = 32; off > 0; off >>= 1) s += __shfl_down(s, off);
    if (lane == 0) out[b] = expf(-s);
}

// ---------------------------------------------------------------------------
extern "C" void kernel_launch(void* const* d_in, const int* in_sizes, int n_in,
                              void* d_out, int out_size, void* d_ws, size_t ws_size,
                              hipStream_t stream)
{
    const int*   s1  = (const int*)d_in[0];
    const int*   s2  = (const int*)d_in[1];
    const float* emb = (const float*)d_in[2];
    const float* Wih = (const float*)d_in[3];
    const float* Whh = (const float*)d_in[4];
    const float* bih = (const float*)d_in[5];
    const float* bhh = (const float*)d_in[6];
    const float* h0a = (const float*)d_in[7];
    const float* c0a = (const float*)d_in[8];
    const float* h0b = (const float*)d_in[9];
    const float* c0b = (const float*)d_in[10];
    float* out = (float*)d_out;

    char* ws = (char*)d_ws;
    size_t off = 0;
    unsigned short* WcatP = (unsigned short*)(ws + off); off += (size_t)G4 * KW * 2;   // 2 MB
    unsigned short* WihP  = (unsigned short*)(ws + off); off += (size_t)G4 * KX * 2;   // 1.3 MB
    float* biasP          = (float*)(ws + off);          off += (size_t)G4 * 4;
    unsigned short* hhi0  = (unsigned short*)(ws + off); off += (size_t)BT * HH * 2;
    unsigned short* hhi1  = (unsigned short*)(ws + off); off += (size_t)BT * HH * 2;
    unsigned short* hlo0  = (unsigned short*)(ws + off); off += (size_t)BT * HH * 2;
    unsigned short* hlo1  = (unsigned short*)(ws + off); off += (size_t)BT * HH * 2;
    float* cbuf           = (float*)(ws + off);          off += (size_t)BT * HH * 4;   // 1 MB
    unsigned short* Xbf   = (unsigned short*)(ws + off); off += (size_t)TT * BT * KX * 2; // 21 MB
    unsigned short* xprojP= (unsigned short*)(ws + off); off += (size_t)TT * BT * G4 * 2; // 134 MB

    prep_w<<<G4, 256, 0, stream>>>(Wih, Whh, bih, bhh, WcatP, WihP, biasP);
    prep_h<<<BT, 256, 0, stream>>>(h0a, c0a, h0b, c0b, hhi0, hlo0, cbuf);
    gather_x<<<(TT * BT * 40) / 256, 256, 0, stream>>>(s1, s2, emb, Xbf);
    gemm_x<<<4096, 512, 0, stream>>>(Xbf, WihP, xprojP);

    unsigned short* hhi[2] = { hhi0, hhi1 };
    unsigned short* hlo[2] = { hlo0, hlo1 };
    for (int t = 0; t < TT; ++t) {
        int pi = t & 1, po = pi ^ 1;
        lstm_step<<<256, 256, 0, stream>>>(WcatP, biasP, xprojP,
                                           hhi[pi], hlo[pi], cbuf,
                                           hhi[po], hlo[po], t);
    }
    // t=63 (odd) writes buffer 0
    finalize<<<BB, 64, 0, stream>>>(hhi0, hlo0, out);
}